// Round 10
// baseline (48.876 us; speedup 1.0000x reference)
//
#include <hip/hip_runtime.h>
#include <stdint.h>

// VQ-VAE quantization: B=131072 rows of z (D=64) vs N_E=1024 codes.
// Outputs (flat f32): z_q [131072*64] | loss [1] | idx [131072] | var(idx,ddof=1) [1]
//
// R10: operand-reuse + register-depth round (m93 lever):
//  - 64 rows/wave (4 z-subtiles): each e-frag LDS read feeds 8 MFMAs (was 4),
//    4 independent MFMA dep-chains per tile (was 2).
//  - explicit 4-tile fragment groups into registers before compute; compiler
//    inserts counted lgkmcnt between group load and use.
//  - v_and_or_b32 packed keys (8 VALU / 4 candidates, was 13).
//  - triple-buffered LDS, one barrier/phase, counted vmcnt(4), setprio.
// key = (float_bits(0.5+||e||^2-2z.e) & ~1023) | code ; unsigned min == argmin.

typedef __attribute__((ext_vector_type(8))) __bf16 bf16x8;
typedef __attribute__((ext_vector_type(4))) float f32x4;

#define OUT_LOSS 8388608
#define OUT_IDX  8388609
#define OUT_VAR  8519681

// workspace layout (bytes)
#define WS_LOSS  0          // float[512] per-block loss partials
#define WS_S1    4096       // int[512] sum(idx)
#define WS_S2    8192       // int[512] sum(idx^2)
#define WS_EFRAG 12288      // bf16x8[64 tiles * 2 ksteps * 64 lanes] = 128 KB
#define WS_EE    143360     // float[1024] ||e||^2 + 0.5 (4 KB)

__device__ __forceinline__ void gld_lds16(const void* g, void* l) {
  __builtin_amdgcn_global_load_lds(
      (const __attribute__((address_space(1))) unsigned*)g,
      (__attribute__((address_space(3))) unsigned*)l, 16, 0, 0);
}

// ---- K0: prep codebook fragments -----------------------------------------
// A-frag for mfma_f32_16x16x32_bf16: lane l holds code row (t*16 + (l&15)),
// k = kstep*32 + (l>>4)*8 + i. Values are -2*e.
__global__ void vq_prep(const float* __restrict__ emb, char* __restrict__ ws) {
  bf16x8* efrag = (bf16x8*)(ws + WS_EFRAG);
  float* eeoff = (float*)(ws + WS_EE);
  const int t = blockIdx.x;    // tile 0..63
  const int l = threadIdx.x;   // 0..63
  const int n = t * 16 + (l & 15);
  const int kb0 = (l >> 4) * 8;
  const float* er = emb + n * 64;
  for (int j = 0; j < 2; ++j) {
    const int kb = j * 32 + kb0;
    bf16x8 h;
#pragma unroll
    for (int i = 0; i < 8; ++i) h[i] = (__bf16)(-2.0f * er[kb + i]);
    efrag[(t * 2 + j) * 64 + l] = h;
  }
  if (l < 16) {
    const float* e2 = emb + (t * 16 + l) * 64;
    float s = 0.f;
#pragma unroll
    for (int d = 0; d < 64; ++d) s += e2[d] * e2[d];
    eeoff[t * 16 + l] = s + 0.5f;
  }
}

// ---- K1: distances + argmin + fused epilogue ------------------------------
// 512 blocks x 256 thr (4 waves); wave w owns rows blockIdx*256 + w*64 .. +63.
__global__ void __launch_bounds__(256) vq_main(
    const float* __restrict__ z, const float* __restrict__ emb,
    float* __restrict__ out, char* __restrict__ ws) {
  __shared__ char smfrag[3][16384];   // triple-buffered 8-tile phases
  __shared__ float see[1024];         // ||e||^2 + 0.5 table
  __shared__ float sL[4];
  __shared__ int sA[4], sB[4];

  const int tid = threadIdx.x;
  const int wave = tid >> 6, lane = tid & 63;
  const int lr = lane & 15, ksl = lane >> 4;
  const int k0 = ksl * 8;
  const int row_base = blockIdx.x * 256 + wave * 64;

#define STAGE(ph, buf)                                                          \
  {                                                                             \
    _Pragma("unroll")                                                           \
    for (int i_ = 0; i_ < 4; ++i_)                                              \
      gld_lds16(ws + WS_EFRAG + (ph) * 16384 + wave * 4096 + i_ * 1024 + lane * 16, \
                smfrag[buf] + wave * 4096 + i_ * 1024);                         \
  }

  // z loads FIRST (oldest in vmcnt queue): 4 subtiles x 4 f32x4 = 64 VGPR burst
  f32x4 zr[16];
#pragma unroll
  for (int r = 0; r < 4; ++r) {
    const float* zp = z + (size_t)(row_base + r * 16 + lr) * 64;
    zr[r * 4 + 0] = *(const f32x4*)(zp + k0);
    zr[r * 4 + 1] = *(const f32x4*)(zp + k0 + 4);
    zr[r * 4 + 2] = *(const f32x4*)(zp + 32 + k0);
    zr[r * 4 + 3] = *(const f32x4*)(zp + 32 + k0 + 4);
  }

  // async staging: ee table + phases 0,1 (9 loads/wave, stay in flight)
  gld_lds16(ws + WS_EE + wave * 1024 + lane * 16, (char*)see + wave * 1024);
  STAGE(0, 0);
  STAGE(1, 1);

  // convert z to bf16 B-fragments + ||z||^2 (compiler waits for z counted,
  // leaving staging loads in flight)
  bf16x8 zf[4][2];
  float zz[4];
#pragma unroll
  for (int r = 0; r < 4; ++r) {
    float s = 0.f;
#pragma unroll
    for (int i = 0; i < 4; ++i) {
      zf[r][0][i] = (__bf16)zr[r * 4 + 0][i]; zf[r][0][4 + i] = (__bf16)zr[r * 4 + 1][i];
      zf[r][1][i] = (__bf16)zr[r * 4 + 2][i]; zf[r][1][4 + i] = (__bf16)zr[r * 4 + 3][i];
      s += zr[r * 4 + 0][i] * zr[r * 4 + 0][i] + zr[r * 4 + 1][i] * zr[r * 4 + 1][i]
         + zr[r * 4 + 2][i] * zr[r * 4 + 2][i] + zr[r * 4 + 3][i] * zr[r * 4 + 3][i];
    }
    s += __shfl_xor(s, 16, 64);
    s += __shfl_xor(s, 32, 64);
    zz[r] = s;
  }

  unsigned rk[4];
#pragma unroll
  for (int r = 0; r < 4; ++r) rk[r] = 0xFFFFFFFFu;
  const unsigned kj0 = (unsigned)(ksl * 4), kj1 = kj0 + 1, kj2 = kj0 + 2, kj3 = kj0 + 3;

  for (int ph = 0; ph < 8; ++ph) {
    // this wave's stage(ph) done; barrier then makes ALL waves' stage(ph) visible
    if (ph < 7) { asm volatile("s_waitcnt vmcnt(4)" ::: "memory"); }
    else        { asm volatile("s_waitcnt vmcnt(0)" ::: "memory"); }
    __builtin_amdgcn_sched_barrier(0);
    __builtin_amdgcn_s_barrier();       // also retires phase ph-1's readers
    if (ph < 6) STAGE(ph + 2, (ph + 2) % 3);
    const bf16x8* sfrag = (const bf16x8*)(smfrag[ph % 3]);
    __builtin_amdgcn_s_setprio(1);
#pragma unroll
    for (int half = 0; half < 2; ++half) {
      // fragment group -> registers (compiler emits counted lgkmcnt)
      bf16x8 E0[4], E1[4];
      f32x4 EE[4];
#pragma unroll
      for (int q = 0; q < 4; ++q) {
        const int tt = half * 4 + q;
        E0[q] = sfrag[(tt * 2 + 0) * 64 + lane];
        E1[q] = sfrag[(tt * 2 + 1) * 64 + lane];
        EE[q] = *(const f32x4*)(see + (ph * 8 + tt) * 16 + ksl * 4);
      }
#pragma unroll
      for (int q = 0; q < 4; ++q) {
        const unsigned g16 = (unsigned)((ph * 8 + half * 4 + q) * 16);
#pragma unroll
        for (int r = 0; r < 4; ++r) {   // 4 independent MFMA chains
          f32x4 a = __builtin_amdgcn_mfma_f32_16x16x32_bf16(E0[q], zf[r][0], EE[q], 0, 0, 0);
          a = __builtin_amdgcn_mfma_f32_16x16x32_bf16(E1[q], zf[r][1], a, 0, 0, 0);
          const unsigned t0 = (__float_as_uint(a[0]) & 0xFFFFFC00u) | kj0;  // v_and_or_b32
          const unsigned t1 = (__float_as_uint(a[1]) & 0xFFFFFC00u) | kj1;
          const unsigned t2 = (__float_as_uint(a[2]) & 0xFFFFFC00u) | kj2;
          const unsigned t3 = (__float_as_uint(a[3]) & 0xFFFFFC00u) | kj3;
          const unsigned m = min(min(min(t0, t1), t2), t3);   // min3 + min
          rk[r] = min(rk[r], m + g16);
        }
      }
    }
    __builtin_amdgcn_s_setprio(0);
  }
#undef STAGE

  // per-row final keys: reduce across the 4 ksl lane groups
#pragma unroll
  for (int r = 0; r < 4; ++r) {
    rk[r] = min(rk[r], (unsigned)__shfl_xor((int)rk[r], 16, 64));
    rk[r] = min(rk[r], (unsigned)__shfl_xor((int)rk[r], 32, 64));
  }

  // fused epilogue: 2 halves x (2 lanes per row, 32 rows); gather z_q,
  // write idx, accumulate loss/var partials.
  float ls = 0.f; int s1 = 0, s2 = 0;
  const int erow = lane >> 1, eseg = lane & 1;
  const int src = erow & 15;     // lane holding this row's key/zz
  const int hi = erow >> 4;      // which subtile within the half
#pragma unroll
  for (int h = 0; h < 2; ++h) {
    const unsigned ka = (unsigned)__shfl((int)rk[h * 2 + 0], src, 64);
    const unsigned kb = (unsigned)__shfl((int)rk[h * 2 + 1], src, 64);
    const float za = __shfl(zz[h * 2 + 0], src, 64);
    const float zb = __shfl(zz[h * 2 + 1], src, 64);
    const unsigned k = hi ? kb : ka;
    const float zzv = hi ? zb : za;
    const unsigned idx = k & 1023u;
    const size_t rowg = (size_t)row_base + h * 32 + erow;
    const f32x4* ep = (const f32x4*)(emb + (size_t)idx * 64 + eseg * 32);
    f32x4* op = (f32x4*)(out + rowg * 64 + eseg * 32);
#pragma unroll
    for (int c = 0; c < 8; ++c) op[c] = ep[c];
    if (eseg == 0) {
      // d = ||z||^2 + (0.5 + ee - 2 z.e)_min - 0.5 ; low 10 bits cleared
      ls += zzv + __uint_as_float(k & 0xFFFFFC00u) - 0.5f;
      s1 += (int)idx;
      s2 += (int)(idx * idx);
      out[OUT_IDX + rowg] = (float)idx;
    }
  }
#pragma unroll
  for (int off = 1; off < 64; off <<= 1) {
    ls += __shfl_xor(ls, off, 64);
    s1 += __shfl_xor(s1, off, 64);
    s2 += __shfl_xor(s2, off, 64);
  }
  if (lane == 0) { sL[wave] = ls; sA[wave] = s1; sB[wave] = s2; }
  __syncthreads();
  if (tid == 0) {
    float L = 0; int a = 0, b = 0;
#pragma unroll
    for (int w = 0; w < 4; ++w) { L += sL[w]; a += sA[w]; b += sB[w]; }
    ((float*)(ws + WS_LOSS))[blockIdx.x] = L;
    ((int*)(ws + WS_S1))[blockIdx.x] = a;
    ((int*)(ws + WS_S2))[blockIdx.x] = b;
  }
}

// ---- K2: final scalar reduce over 512 block partials ----------------------
__global__ void vq_final(float* __restrict__ out, const char* __restrict__ ws) {
  const int t = threadIdx.x;   // 256 threads
  const float* lp = (const float*)(ws + WS_LOSS);
  const int* p1 = (const int*)(ws + WS_S1);
  const int* p2 = (const int*)(ws + WS_S2);
  double L = 0; long long a = 0, b = 0;
#pragma unroll
  for (int kk = 0; kk < 2; ++kk) {
    const int i = t + 256 * kk;
    L += (double)lp[i];
    a += (long long)p1[i];
    b += (long long)p2[i];
  }
#pragma unroll
  for (int off = 1; off < 64; off <<= 1) {
    L += __shfl_xor(L, off, 64);
    a += __shfl_xor(a, off, 64);
    b += __shfl_xor(b, off, 64);
  }
  __shared__ double sLf[4];
  __shared__ long long sAf[4], sBf[4];
  const int wave = t >> 6, lane = t & 63;
  if (lane == 0) { sLf[wave] = L; sAf[wave] = a; sBf[wave] = b; }
  __syncthreads();
  if (t == 0) {
    double Lt = 0; long long at = 0, bt = 0;
#pragma unroll
    for (int w = 0; w < 4; ++w) { Lt += sLf[w]; at += sAf[w]; bt += sBf[w]; }
    // loss = (beta + 1) * mean((z_q - z)^2), beta = 0.25
    out[OUT_LOSS] = (float)(1.25 * Lt / 8388608.0);
    // var(idx, ddof=1) exact: (n*S2 - S1^2) / (n*(n-1))
    long long num = bt * 131072LL - at * at;
    out[OUT_VAR] = (float)((double)num / (131072.0 * 131071.0));
  }
}

extern "C" void kernel_launch(void* const* d_in, const int* in_sizes, int n_in,
                              void* d_out, int out_size, void* d_ws, size_t ws_size,
                              hipStream_t stream) {
  (void)in_sizes; (void)n_in; (void)out_size; (void)ws_size;
  const float* z = (const float*)d_in[0];
  const float* emb = (const float*)d_in[1];
  float* out = (float*)d_out;
  char* ws = (char*)d_ws;
  vq_prep<<<64, 64, 0, stream>>>(emb, ws);
  vq_main<<<512, 256, 0, stream>>>(z, emb, out, ws);
  vq_final<<<1, 256, 0, stream>>>(out, ws);
}